// Round 6
// baseline (276.330 us; speedup 1.0000x reference)
//
#include <hip/hip_runtime.h>
#include <hip/hip_bf16.h>
#include <math.h>

#define NDIM 768
#define NHEADS 12
#define HD 64
#define SEQ 1024
#define BATCH 8
#define MROWS (BATCH * SEQ)          // 8192
#define SQRT_DIM 27.712812921102035f // 1/SCALE_PARAM_INIT
#define LOG2E 1.4426950408889634f

typedef unsigned short u16;
typedef unsigned int u32;
typedef __attribute__((ext_vector_type(8))) short short8;   // 8 bf16 = 4 VGPRs
typedef __attribute__((ext_vector_type(4))) short bf16x4;   // 4 bf16 = 2 VGPRs
typedef __attribute__((ext_vector_type(4))) float f32x4;
typedef __attribute__((ext_vector_type(16))) float f32x16;

#define MFMA16(a, b, c) __builtin_amdgcn_mfma_f32_16x16x32_bf16(a, b, c, 0, 0, 0)
#define MFMA32(a, b, c) __builtin_amdgcn_mfma_f32_32x32x16_bf16(a, b, c, 0, 0, 0)

__device__ inline u16 f2bf(float f) {
    __hip_bfloat16 h = __float2bfloat16(f);
    return *reinterpret_cast<u16*>(&h);
}
__device__ inline float bf2f(u16 u) {
    u32 w = ((u32)u) << 16;
    return __builtin_bit_cast(float, w);
}

// async 16B global->LDS. LDS dest is wave-uniform base; HW adds lane*16.
__device__ inline void gl2lds16(const void* g, void* l) {
    __builtin_amdgcn_global_load_lds((const __attribute__((address_space(1))) void*)g,
                                     (__attribute__((address_space(3))) void*)l, 16, 0, 0);
}

// ---------------------------------------------------------------------------
// One fused cast kernel: x (6144 blocks) + Wq/Wk/Wv -> Wqkv, Wo -> Wob.
// ---------------------------------------------------------------------------
__global__ __launch_bounds__(256) void castall(const float* __restrict__ x,
                                               const float* __restrict__ Wq,
                                               const float* __restrict__ Wk,
                                               const float* __restrict__ Wv,
                                               const float* __restrict__ Wo,
                                               u16* __restrict__ xb,
                                               u16* __restrict__ Wqkv,
                                               u16* __restrict__ Wob) {
    const int WB = (NDIM * NDIM) / 1024; // 576 blocks per weight
    int blk = blockIdx.x;
    const float* s;
    u16* d;
    int base;
    if (blk < 6144) {
        s = x; d = xb; base = blk * 1024;
    } else {
        int wsel = (blk - 6144) / WB, r = (blk - 6144) % WB;
        base = r * 1024;
        if (wsel == 0)      { s = Wq; d = Wqkv; }
        else if (wsel == 1) { s = Wk; d = Wqkv + NDIM * NDIM; }
        else if (wsel == 2) { s = Wv; d = Wqkv + 2 * NDIM * NDIM; }
        else                { s = Wo; d = Wob; }
    }
    int i = base + threadIdx.x * 4;
    float4 v = *(const float4*)(s + i);
    d[i] = f2bf(v.x); d[i + 1] = f2bf(v.y); d[i + 2] = f2bf(v.z); d[i + 3] = f2bf(v.w);
}

// ---------------------------------------------------------------------------
// bf16 MFMA GEMM: C = A[M,768] @ B[N,768]^T, fp32 accum. 128x128 tile, BK=32,
// 4 waves (2x2 of 64x64). Chunk-transposed LDS (slot = kc*128+row).
// EPI 0: fp32 row-major C.  EPI 1: bf16 transposed into Vt[b,h,d,tok].
// EPI 2: cosine-norm + s_eff + bf16 to Qh/Kh [b,h,tok,64]; q gets 8*log2e.
// ---------------------------------------------------------------------------
template <int EPI>
__global__ __launch_bounds__(256) void gemm_bf16(const u16* __restrict__ A,
                                                 const u16* __restrict__ B,
                                                 void* __restrict__ C, int N,
                                                 const float* __restrict__ s_qk,
                                                 u16* __restrict__ Qdst,
                                                 u16* __restrict__ Kdst) {
    constexpr int K = NDIM;
    __shared__ __align__(16) u16 As[512 * 8];
    __shared__ __align__(16) u16 Bs[512 * 8];
    const int t = threadIdx.x;
    const int wave = t >> 6, lane = t & 63;
    const int quad = lane >> 4, l16 = lane & 15;
    const int wx = (wave & 1) * 64, wy = (wave >> 1) * 64;
    const int bm = blockIdx.y * 128, bn = blockIdx.x * 128;

    f32x4 acc[4][4];
#pragma unroll
    for (int i = 0; i < 4; ++i)
#pragma unroll
        for (int j = 0; j < 4; ++j) acc[i][j] = (f32x4){0.f, 0.f, 0.f, 0.f};

    for (int k0 = 0; k0 < K; k0 += 32) {
        __syncthreads();
#pragma unroll
        for (int it = 0; it < 2; ++it) {
            const int cb = it * 256 + wave * 64;
            const int kc = cb >> 7;
            const int row = (cb & 127) + lane;
            gl2lds16(A + (size_t)(bm + row) * K + k0 + kc * 8, (char*)As + cb * 16);
            gl2lds16(B + (size_t)(bn + row) * K + k0 + kc * 8, (char*)Bs + cb * 16);
        }
        asm volatile("s_waitcnt vmcnt(0)" ::: "memory");
        __syncthreads();

        short8 af[4], bf[4];
#pragma unroll
        for (int i = 0; i < 4; ++i)
            af[i] = *(const short8*)&As[(quad * 128 + wy + i * 16 + l16) * 8];
#pragma unroll
        for (int j = 0; j < 4; ++j)
            bf[j] = *(const short8*)&Bs[(quad * 128 + wx + j * 16 + l16) * 8];
#pragma unroll
        for (int i = 0; i < 4; ++i)
#pragma unroll
            for (int j = 0; j < 4; ++j) acc[i][j] = MFMA16(af[i], bf[j], acc[i][j]);
    }

    if constexpr (EPI == 0) {
#pragma unroll
        for (int i = 0; i < 4; ++i)
#pragma unroll
            for (int j = 0; j < 4; ++j)
#pragma unroll
                for (int r = 0; r < 4; ++r) {
                    const int row = bm + wy + i * 16 + quad * 4 + r;
                    const int col = bn + wx + j * 16 + l16;
                    ((float*)C)[(size_t)row * N + col] = acc[i][j][r];
                }
    } else if constexpr (EPI == 1) {
#pragma unroll
        for (int i = 0; i < 4; ++i)
#pragma unroll
            for (int j = 0; j < 4; ++j)
#pragma unroll
                for (int r = 0; r < 4; ++r) {
                    const int row = bm + wy + i * 16 + quad * 4 + r; // token
                    const int col = bn + wx + j * 16 + l16;          // h*64+d
                    const int b = row >> 10, n = row & 1023;
                    const int h = col >> 6, dd = col & 63;
                    ((u16*)C)[(((size_t)(b * NHEADS + h) * HD + dd) << 10) + n] =
                        f2bf(acc[i][j][r]);
                }
    } else {
        const int cg = (bn + wx) >> 6; // 0..23
        const bool isq = cg < NHEADS;
        const int h = isq ? cg : cg - NHEADS;
        u16* dst = isq ? Qdst : Kdst;
        const float ex = isq ? 8.f * LOG2E : 1.f;
        float sq[4];
#pragma unroll
        for (int j = 0; j < 4; ++j)
            sq[j] = s_qk[h * HD + j * 16 + l16] * SQRT_DIM * ex;
#pragma unroll
        for (int i = 0; i < 4; ++i)
#pragma unroll
            for (int r = 0; r < 4; ++r) {
                float ss = 0.f;
#pragma unroll
                for (int j = 0; j < 4; ++j) ss += acc[i][j][r] * acc[i][j][r];
                ss += __shfl_xor(ss, 1, 64);
                ss += __shfl_xor(ss, 2, 64);
                ss += __shfl_xor(ss, 4, 64);
                ss += __shfl_xor(ss, 8, 64);
                float inv = 1.f / fmaxf(sqrtf(ss), 1e-6f);
                const int row = bm + wy + i * 16 + quad * 4 + r;
                const int b = row >> 10, tok = row & 1023;
                u16* o = dst + ((size_t)(b * NHEADS + h) * SEQ + tok) * HD;
#pragma unroll
                for (int j = 0; j < 4; ++j)
                    o[j * 16 + l16] = f2bf(acc[i][j][r] * sq[j] * inv);
            }
    }
}

// ---------------------------------------------------------------------------
// MFMA flash attention, 32x32x16, no-max softmax (logits bounded by cosine
// norm). Each wave owns 64 queries (2 col-tiles of 32); block = 2 waves =
// 128 queries; streams 64-key tiles.
//   S^T = MFMA(A=K, B=Q):  D col = query, rows = keys -> per-lane row sums,
//   packed b64 P writes (consecutive regs = consecutive keys).
//   O^T = MFMA(A=V^T, B=P): B-frag of P is a contiguous, 16B-ALIGNED b128.
// Qh/Kh: [b,h,tok,64] bf16 (q pre-scaled by 8*log2e), Vt: [b,h,d,tok] bf16.
// K/V LDS chunk-transposed (slot = chunk*64 + row). P stride 80 u16 = 160 B
// (16B-aligned rows — stride 76 made odd rows 8-mod-16 and broke b128 reads).
// l is accumulated from the bf16-ROUNDED p so numerator/denominator errors
// correlate and cancel.
// ---------------------------------------------------------------------------
__global__ __launch_bounds__(128) void attn_mfma(const u16* __restrict__ Qh,
                                                 const u16* __restrict__ Kh,
                                                 const u16* __restrict__ Vt,
                                                 u16* __restrict__ AO) {
    __shared__ __align__(16) u16 Ks[512 * 8];     // slot = dimchunk*64 + key
    __shared__ __align__(16) u16 Vs[512 * 8];     // slot = keychunk*64 + d
    __shared__ __align__(16) u16 Ps[2][64][80];   // [wave][q_local][key]

    const int t = threadIdx.x;
    const int wave = t >> 6, lane = t & 63;
    const int l31 = lane & 31, half = lane >> 5;
    const int b = blockIdx.z, h = blockIdx.y, q0 = blockIdx.x * 128;
    const int bh = b * NHEADS + h;
    const u16* Kb = Kh + (size_t)bh * SEQ * HD;
    const u16* Vb = Vt + (size_t)bh * HD * SEQ;
    const int qb = q0 + wave * 64;

    // Q fragments (B-operand: n=q=l31, k = half*8+j within each 16-dim tile)
    short8 qf[2][4];
#pragma unroll
    for (int qt = 0; qt < 2; ++qt)
#pragma unroll
        for (int tt = 0; tt < 4; ++tt)
            qf[qt][tt] = *(const short8*)(Qh + ((size_t)bh * SEQ + qb + qt * 32 + l31) * HD +
                                          tt * 16 + half * 8);

    f32x16 o[2][2]; // [d-tile][q-tile]
#pragma unroll
    for (int dt = 0; dt < 2; ++dt)
#pragma unroll
        for (int qt = 0; qt < 2; ++qt)
#pragma unroll
            for (int r = 0; r < 16; ++r) o[dt][qt][r] = 0.f;
    float lp[2] = {0.f, 0.f};

    for (int j0 = 0; j0 < SEQ; j0 += 64) {
        __syncthreads();
#pragma unroll
        for (int it = 0; it < 4; ++it) {
            const int cb = it * 128 + wave * 64; // slot base, wave-uniform
            const int c8 = cb >> 6;              // chunk index 0..7
            gl2lds16(Kb + (size_t)(j0 + lane) * HD + c8 * 8, (char*)Ks + cb * 16);
            gl2lds16(Vb + (size_t)lane * SEQ + j0 + c8 * 8, (char*)Vs + cb * 16);
        }
        asm volatile("s_waitcnt vmcnt(0)" ::: "memory");
        __syncthreads();

        // ---- S^T phase: per 32-key tile, accumulate over 64 dims ----
#pragma unroll
        for (int kt = 0; kt < 2; ++kt) {
            f32x16 sa[2];
#pragma unroll
            for (int qt = 0; qt < 2; ++qt)
#pragma unroll
                for (int r = 0; r < 16; ++r) sa[qt][r] = 0.f;
#pragma unroll
            for (int tt = 0; tt < 4; ++tt) {
                short8 kf = *(const short8*)&Ks[((2 * tt + half) * 64 + kt * 32 + l31) * 8];
                sa[0] = MFMA32(kf, qf[0][tt], sa[0]);
                sa[1] = MFMA32(kf, qf[1][tt], sa[1]);
            }
            // exp2 (log2-domain logits), bf16 round, consistent l, packed write
#pragma unroll
            for (int qt = 0; qt < 2; ++qt) {
#pragma unroll
                for (int rg = 0; rg < 4; ++rg) {
                    u16 b0 = f2bf(exp2f(sa[qt][rg * 4 + 0]));
                    u16 b1 = f2bf(exp2f(sa[qt][rg * 4 + 1]));
                    u16 b2 = f2bf(exp2f(sa[qt][rg * 4 + 2]));
                    u16 b3 = f2bf(exp2f(sa[qt][rg * 4 + 3]));
                    lp[qt] += (bf2f(b0) + bf2f(b1)) + (bf2f(b2) + bf2f(b3));
                    bf16x4 pk = {(short)b0, (short)b1, (short)b2, (short)b3};
                    *(bf16x4*)&Ps[wave][qt * 32 + l31][kt * 32 + rg * 8 + half * 4] = pk;
                }
            }
        }

        // ---- PV phase: O^T += V^T @ P^T (own-wave P; lgkm wait by compiler)
        short8 pf[2][4];
#pragma unroll
        for (int qt = 0; qt < 2; ++qt)
#pragma unroll
            for (int k2 = 0; k2 < 4; ++k2)
                pf[qt][k2] = *(const short8*)&Ps[wave][qt * 32 + l31][k2 * 16 + half * 8];
#pragma unroll
        for (int dt = 0; dt < 2; ++dt)
#pragma unroll
            for (int k2 = 0; k2 < 4; ++k2) {
                short8 vf = *(const short8*)&Vs[((2 * k2 + half) * 64 + dt * 32 + l31) * 8];
                o[dt][0] = MFMA32(vf, pf[0][k2], o[dt][0]);
                o[dt][1] = MFMA32(vf, pf[1][k2], o[dt][1]);
            }
    }

    // final l reduction (halves hold disjoint key subsets) and output
    float invl[2];
#pragma unroll
    for (int qt = 0; qt < 2; ++qt) {
        float l = lp[qt] + __shfl_xor(lp[qt], 32, 64);
        invl[qt] = 1.f / l;
    }
#pragma unroll
    for (int qt = 0; qt < 2; ++qt) {
        u16* ob = AO + (size_t)(b * SEQ + qb + qt * 32 + l31) * NDIM + h * HD;
#pragma unroll
        for (int dt = 0; dt < 2; ++dt)
#pragma unroll
            for (int rg = 0; rg < 4; ++rg) {
                bf16x4 ok = {(short)f2bf(o[dt][qt][rg * 4 + 0] * invl[qt]),
                             (short)f2bf(o[dt][qt][rg * 4 + 1] * invl[qt]),
                             (short)f2bf(o[dt][qt][rg * 4 + 2] * invl[qt]),
                             (short)f2bf(o[dt][qt][rg * 4 + 3] * invl[qt])};
                *(bf16x4*)(ob + dt * 32 + rg * 8 + half * 4) = ok;
            }
    }
}

// ---------------------------------------------------------------------------
extern "C" void kernel_launch(void* const* d_in, const int* in_sizes, int n_in,
                              void* d_out, int out_size, void* d_ws, size_t ws_size,
                              hipStream_t stream) {
    const float* x    = (const float*)d_in[0];
    const float* Wq   = (const float*)d_in[1];
    const float* Wk   = (const float*)d_in[2];
    const float* Wv   = (const float*)d_in[3];
    const float* Wo   = (const float*)d_in[4];
    const float* s_qk = (const float*)d_in[5];
    float* out = (float*)d_out;

    char* w = (char*)d_ws;
    const size_t TE = (size_t)MROWS * NDIM;
    u16* xb   = (u16*)w;                    w += TE * 2;
    u16* Wqkv = (u16*)w;                    w += (size_t)3 * NDIM * NDIM * 2;
    u16* Wob  = (u16*)w;                    w += (size_t)NDIM * NDIM * 2;
    u16* Qh   = (u16*)w;                    w += TE * 2;
    u16* Kh   = (u16*)w;                    w += TE * 2;
    u16* Vt   = (u16*)w;                    w += TE * 2;
    u16* ao   = (u16*)w;

    castall<<<6144 + 4 * 576, 256, 0, stream>>>(x, Wq, Wk, Wv, Wo, xb, Wqkv, Wob);

    gemm_bf16<2><<<dim3(1536 / 128, MROWS / 128), 256, 0, stream>>>(
        xb, Wqkv, nullptr, 1536, s_qk, Qh, Kh);
    gemm_bf16<1><<<dim3(NDIM / 128, MROWS / 128), 256, 0, stream>>>(
        xb, Wqkv + 2 * NDIM * NDIM, (void*)Vt, NDIM, nullptr, nullptr, nullptr);

    attn_mfma<<<dim3(SEQ / 128, NHEADS, BATCH), 128, 0, stream>>>(Qh, Kh, Vt, ao);

    gemm_bf16<0><<<dim3(NDIM / 128, MROWS / 128), 256, 0, stream>>>(
        ao, Wob, out, NDIM, nullptr, nullptr, nullptr);
}

// Round 7
// 254.972 us; speedup vs baseline: 1.0838x; 1.0838x over previous
//
#include <hip/hip_runtime.h>
#include <hip/hip_bf16.h>
#include <math.h>

#define NDIM 768
#define NHEADS 12
#define HD 64
#define SEQ 1024
#define BATCH 8
#define MROWS (BATCH * SEQ)          // 8192
#define SQRT_DIM 27.712812921102035f // 1/SCALE_PARAM_INIT
#define LOG2E 1.4426950408889634f

typedef unsigned short u16;
typedef unsigned int u32;
typedef __attribute__((ext_vector_type(8))) short short8;   // 8 bf16 = 4 VGPRs
typedef __attribute__((ext_vector_type(4))) short bf16x4;   // 4 bf16 = 2 VGPRs
typedef __attribute__((ext_vector_type(4))) float f32x4;
typedef __attribute__((ext_vector_type(16))) float f32x16;

#define MFMA16(a, b, c) __builtin_amdgcn_mfma_f32_16x16x32_bf16(a, b, c, 0, 0, 0)
#define MFMA32(a, b, c) __builtin_amdgcn_mfma_f32_32x32x16_bf16(a, b, c, 0, 0, 0)

__device__ inline u16 f2bf(float f) {
    __hip_bfloat16 h = __float2bfloat16(f);
    return *reinterpret_cast<u16*>(&h);
}
__device__ inline float bf2f(u16 u) {
    u32 w = ((u32)u) << 16;
    return __builtin_bit_cast(float, w);
}

// async 16B global->LDS. LDS dest is wave-uniform base; HW adds lane*16.
__device__ inline void gl2lds16(const void* g, void* l) {
    __builtin_amdgcn_global_load_lds((const __attribute__((address_space(1))) void*)g,
                                     (__attribute__((address_space(3))) void*)l, 16, 0, 0);
}

// ---------------------------------------------------------------------------
// One fused cast kernel: x (6144 blocks) + Wq/Wk/Wv -> Wqkv, Wo -> Wob.
// ---------------------------------------------------------------------------
__global__ __launch_bounds__(256) void castall(const float* __restrict__ x,
                                               const float* __restrict__ Wq,
                                               const float* __restrict__ Wk,
                                               const float* __restrict__ Wv,
                                               const float* __restrict__ Wo,
                                               u16* __restrict__ xb,
                                               u16* __restrict__ Wqkv,
                                               u16* __restrict__ Wob) {
    const int WB = (NDIM * NDIM) / 1024; // 576 blocks per weight
    int blk = blockIdx.x;
    const float* s;
    u16* d;
    int base;
    if (blk < 6144) {
        s = x; d = xb; base = blk * 1024;
    } else {
        int wsel = (blk - 6144) / WB, r = (blk - 6144) % WB;
        base = r * 1024;
        if (wsel == 0)      { s = Wq; d = Wqkv; }
        else if (wsel == 1) { s = Wk; d = Wqkv + NDIM * NDIM; }
        else if (wsel == 2) { s = Wv; d = Wqkv + 2 * NDIM * NDIM; }
        else                { s = Wo; d = Wob; }
    }
    int i = base + threadIdx.x * 4;
    float4 v = *(const float4*)(s + i);
    d[i] = f2bf(v.x); d[i + 1] = f2bf(v.y); d[i + 2] = f2bf(v.z); d[i + 3] = f2bf(v.w);
}

// ---------------------------------------------------------------------------
// bf16 MFMA GEMM: C = A[M,768] @ B[N,768]^T, fp32 accum. 128x128 tile, BK=32,
// 4 waves (2x2 of 64x64). Chunk-transposed LDS (slot = kc*128+row).
// EPI 0: fp32 row-major C.
// EPI 2: fused QKV epilogue (N=2304): per-64-col head group —
//   groups 0..11  = q: cosine-norm + s_eff*8*log2e -> Qdst [b,h,tok,64]
//   groups 12..23 = k: cosine-norm + s_eff         -> Kdst [b,h,tok,64]
//   groups 24..35 = v: bf16 transposed             -> C as Vt [b,h,d,tok]
// ---------------------------------------------------------------------------
template <int EPI>
__global__ __launch_bounds__(256) void gemm_bf16(const u16* __restrict__ A,
                                                 const u16* __restrict__ B,
                                                 void* __restrict__ C, int N,
                                                 const float* __restrict__ s_qk,
                                                 u16* __restrict__ Qdst,
                                                 u16* __restrict__ Kdst) {
    constexpr int K = NDIM;
    __shared__ __align__(16) u16 As[512 * 8];
    __shared__ __align__(16) u16 Bs[512 * 8];
    const int t = threadIdx.x;
    const int wave = t >> 6, lane = t & 63;
    const int quad = lane >> 4, l16 = lane & 15;
    const int wx = (wave & 1) * 64, wy = (wave >> 1) * 64;
    const int bm = blockIdx.y * 128, bn = blockIdx.x * 128;

    f32x4 acc[4][4];
#pragma unroll
    for (int i = 0; i < 4; ++i)
#pragma unroll
        for (int j = 0; j < 4; ++j) acc[i][j] = (f32x4){0.f, 0.f, 0.f, 0.f};

    for (int k0 = 0; k0 < K; k0 += 32) {
        __syncthreads();
#pragma unroll
        for (int it = 0; it < 2; ++it) {
            const int cb = it * 256 + wave * 64;
            const int kc = cb >> 7;
            const int row = (cb & 127) + lane;
            gl2lds16(A + (size_t)(bm + row) * K + k0 + kc * 8, (char*)As + cb * 16);
            gl2lds16(B + (size_t)(bn + row) * K + k0 + kc * 8, (char*)Bs + cb * 16);
        }
        asm volatile("s_waitcnt vmcnt(0)" ::: "memory");
        __syncthreads();

        short8 af[4], bf[4];
#pragma unroll
        for (int i = 0; i < 4; ++i)
            af[i] = *(const short8*)&As[(quad * 128 + wy + i * 16 + l16) * 8];
#pragma unroll
        for (int j = 0; j < 4; ++j)
            bf[j] = *(const short8*)&Bs[(quad * 128 + wx + j * 16 + l16) * 8];
#pragma unroll
        for (int i = 0; i < 4; ++i)
#pragma unroll
            for (int j = 0; j < 4; ++j) acc[i][j] = MFMA16(af[i], bf[j], acc[i][j]);
    }

    if constexpr (EPI == 0) {
#pragma unroll
        for (int i = 0; i < 4; ++i)
#pragma unroll
            for (int j = 0; j < 4; ++j)
#pragma unroll
                for (int r = 0; r < 4; ++r) {
                    const int row = bm + wy + i * 16 + quad * 4 + r;
                    const int col = bn + wx + j * 16 + l16;
                    ((float*)C)[(size_t)row * N + col] = acc[i][j][r];
                }
    } else {
        const int cg = (bn + wx) >> 6; // 0..35
        if (cg >= 2 * NHEADS) {
            // V path: transposed bf16 write into Vt = C
            const int h = cg - 2 * NHEADS;
#pragma unroll
            for (int i = 0; i < 4; ++i)
#pragma unroll
                for (int j = 0; j < 4; ++j)
#pragma unroll
                    for (int r = 0; r < 4; ++r) {
                        const int row = bm + wy + i * 16 + quad * 4 + r; // token
                        const int dd = j * 16 + l16;
                        const int b = row >> 10, n = row & 1023;
                        ((u16*)C)[(((size_t)(b * NHEADS + h) * HD + dd) << 10) + n] =
                            f2bf(acc[i][j][r]);
                    }
        } else {
            const bool isq = cg < NHEADS;
            const int h = isq ? cg : cg - NHEADS;
            u16* dst = isq ? Qdst : Kdst;
            const float ex = isq ? 8.f * LOG2E : 1.f;
            float sq[4];
#pragma unroll
            for (int j = 0; j < 4; ++j)
                sq[j] = s_qk[h * HD + j * 16 + l16] * SQRT_DIM * ex;
#pragma unroll
            for (int i = 0; i < 4; ++i)
#pragma unroll
                for (int r = 0; r < 4; ++r) {
                    float ss = 0.f;
#pragma unroll
                    for (int j = 0; j < 4; ++j) ss += acc[i][j][r] * acc[i][j][r];
                    ss += __shfl_xor(ss, 1, 64);
                    ss += __shfl_xor(ss, 2, 64);
                    ss += __shfl_xor(ss, 4, 64);
                    ss += __shfl_xor(ss, 8, 64);
                    float inv = 1.f / fmaxf(sqrtf(ss), 1e-6f);
                    const int row = bm + wy + i * 16 + quad * 4 + r;
                    const int b = row >> 10, tok = row & 1023;
                    u16* o = dst + ((size_t)(b * NHEADS + h) * SEQ + tok) * HD;
#pragma unroll
                    for (int j = 0; j < 4; ++j)
                        o[j * 16 + l16] = f2bf(acc[i][j][r] * sq[j] * inv);
                }
        }
    }
}

// ---------------------------------------------------------------------------
// MFMA flash attention, 32x32x16, no-max softmax. 256 threads = 4 waves;
// each wave owns 32 queries -> block = 128 queries; streams 64-key tiles.
//   S^T = MFMA(A=K, B=Q): D col = query, consecutive regs = consecutive keys.
//   O^T = MFMA(A=V^T, B=P).
// P buffer: row stride 64 u16 (128 B), XOR-swizzled at 8B-unit granularity
// (phys_unit = u ^ (row & 15)) -> both b64 writes and b64 reads hit 16
// distinct bank-pairs = conflict-free. Reads recombine 2 x b64 into the
// short8 B-operand via shufflevector.
// Qh/Kh: [b,h,tok,64] bf16 (q pre-scaled by 8*log2e), Vt: [b,h,d,tok] bf16.
// l accumulated from bf16-rounded p (numerator/denominator errors cancel).
// ---------------------------------------------------------------------------
__global__ __launch_bounds__(256) void attn_mfma(const u16* __restrict__ Qh,
                                                 const u16* __restrict__ Kh,
                                                 const u16* __restrict__ Vt,
                                                 u16* __restrict__ AO) {
    __shared__ __align__(16) u16 Ks[512 * 8];   // slot = dimchunk*64 + key
    __shared__ __align__(16) u16 Vs[512 * 8];   // slot = keychunk*64 + d
    __shared__ __align__(16) u16 Ps[4 * 32 * 64]; // [wave][qrow][64], swizzled

    const int t = threadIdx.x;
    const int wave = t >> 6, lane = t & 63;
    const int l31 = lane & 31, half = lane >> 5;
    const int b = blockIdx.z, h = blockIdx.y, q0 = blockIdx.x * 128;
    const int bh = b * NHEADS + h;
    const u16* Kb = Kh + (size_t)bh * SEQ * HD;
    const u16* Vb = Vt + (size_t)bh * HD * SEQ;
    const int qb = q0 + wave * 32;
    const int pbase = wave * 2048 + l31 * 64; // this lane's P row (u16 idx)
    const int sw = (l31 & 15);                // XOR key for 8B units

    // Q fragments (B-operand: n = query = l31, k = tt*16 + half*8 + j)
    short8 qf[4];
#pragma unroll
    for (int tt = 0; tt < 4; ++tt)
        qf[tt] = *(const short8*)(Qh + ((size_t)bh * SEQ + qb + l31) * HD +
                                  tt * 16 + half * 8);

    f32x16 o[2]; // [d-tile]
#pragma unroll
    for (int dt = 0; dt < 2; ++dt)
#pragma unroll
        for (int r = 0; r < 16; ++r) o[dt][r] = 0.f;
    float lp = 0.f;

    for (int j0 = 0; j0 < SEQ; j0 += 64) {
        __syncthreads();
#pragma unroll
        for (int it = 0; it < 2; ++it) {
            const int cb = it * 256 + wave * 64; // slot base, wave-uniform
            const int c8 = cb >> 6;              // chunk index 0..7
            gl2lds16(Kb + (size_t)(j0 + lane) * HD + c8 * 8, (char*)Ks + cb * 16);
            gl2lds16(Vb + (size_t)lane * SEQ + j0 + c8 * 8, (char*)Vs + cb * 16);
        }
        asm volatile("s_waitcnt vmcnt(0)" ::: "memory");
        __syncthreads();

        // ---- S^T phase: 64 keys x 32 queries ----
#pragma unroll
        for (int kt = 0; kt < 2; ++kt) {
            f32x16 sa;
#pragma unroll
            for (int r = 0; r < 16; ++r) sa[r] = 0.f;
#pragma unroll
            for (int tt = 0; tt < 4; ++tt) {
                short8 kf = *(const short8*)&Ks[((2 * tt + half) * 64 + kt * 32 + l31) * 8];
                sa = MFMA32(kf, qf[tt], sa);
            }
            // exp2 (log2-domain), bf16 round, consistent l, swizzled b64 write
#pragma unroll
            for (int rg = 0; rg < 4; ++rg) {
                u16 b0 = f2bf(exp2f(sa[rg * 4 + 0]));
                u16 b1 = f2bf(exp2f(sa[rg * 4 + 1]));
                u16 b2 = f2bf(exp2f(sa[rg * 4 + 2]));
                u16 b3 = f2bf(exp2f(sa[rg * 4 + 3]));
                lp += (bf2f(b0) + bf2f(b1)) + (bf2f(b2) + bf2f(b3));
                bf16x4 pk = {(short)b0, (short)b1, (short)b2, (short)b3};
                const int u = kt * 8 + rg * 2 + half; // logical 8B unit
                *(bf16x4*)&Ps[pbase + (u ^ sw) * 4] = pk;
            }
        }

        // ---- PV phase: O^T += V^T @ P (own-wave P; DS pipe is in-order) ----
#pragma unroll
        for (int k2 = 0; k2 < 4; ++k2) {
            const int u0 = k2 * 4 + half * 2;
            bf16x4 lo = *(const bf16x4*)&Ps[pbase + ((u0 + 0) ^ sw) * 4];
            bf16x4 hi = *(const bf16x4*)&Ps[pbase + ((u0 + 1) ^ sw) * 4];
            short8 pf = __builtin_shufflevector(lo, hi, 0, 1, 2, 3, 4, 5, 6, 7);
#pragma unroll
            for (int dt = 0; dt < 2; ++dt) {
                short8 vf = *(const short8*)&Vs[((2 * k2 + half) * 64 + dt * 32 + l31) * 8];
                o[dt] = MFMA32(vf, pf, o[dt]);
            }
        }
    }

    // final l reduction (halves hold disjoint key subsets) and output
    const float invl = 1.f / (lp + __shfl_xor(lp, 32, 64));
    u16* ob = AO + (size_t)(b * SEQ + qb + l31) * NDIM + h * HD;
#pragma unroll
    for (int dt = 0; dt < 2; ++dt)
#pragma unroll
        for (int rg = 0; rg < 4; ++rg) {
            bf16x4 ok = {(short)f2bf(o[dt][rg * 4 + 0] * invl),
                         (short)f2bf(o[dt][rg * 4 + 1] * invl),
                         (short)f2bf(o[dt][rg * 4 + 2] * invl),
                         (short)f2bf(o[dt][rg * 4 + 3] * invl)};
            *(bf16x4*)(ob + dt * 32 + rg * 8 + half * 4) = ok;
        }
}

// ---------------------------------------------------------------------------
extern "C" void kernel_launch(void* const* d_in, const int* in_sizes, int n_in,
                              void* d_out, int out_size, void* d_ws, size_t ws_size,
                              hipStream_t stream) {
    const float* x    = (const float*)d_in[0];
    const float* Wq   = (const float*)d_in[1];
    const float* Wk   = (const float*)d_in[2];
    const float* Wv   = (const float*)d_in[3];
    const float* Wo   = (const float*)d_in[4];
    const float* s_qk = (const float*)d_in[5];
    float* out = (float*)d_out;

    char* w = (char*)d_ws;
    const size_t TE = (size_t)MROWS * NDIM;
    u16* xb   = (u16*)w;                    w += TE * 2;
    u16* Wqkv = (u16*)w;                    w += (size_t)3 * NDIM * NDIM * 2;
    u16* Wob  = (u16*)w;                    w += (size_t)NDIM * NDIM * 2;
    u16* Qh   = (u16*)w;                    w += TE * 2;
    u16* Kh   = (u16*)w;                    w += TE * 2;
    u16* Vt   = (u16*)w;                    w += TE * 2;
    u16* ao   = (u16*)w;

    castall<<<6144 + 4 * 576, 256, 0, stream>>>(x, Wq, Wk, Wv, Wo, xb, Wqkv, Wob);

    // Fused QKV projection: q/k cosine-norm epilogue + transposed V epilogue
    gemm_bf16<2><<<dim3(2304 / 128, MROWS / 128), 256, 0, stream>>>(
        xb, Wqkv, (void*)Vt, 2304, s_qk, Qh, Kh);

    attn_mfma<<<dim3(SEQ / 128, NHEADS, BATCH), 256, 0, stream>>>(Qh, Kh, Vt, ao);

    gemm_bf16<0><<<dim3(NDIM / 128, MROWS / 128), 256, 0, stream>>>(
        ao, Wob, out, NDIM, nullptr, nullptr, nullptr);
}